// Round 5
// baseline (21302.341 us; speedup 1.0000x reference)
//
#include <hip/hip_runtime.h>
#include <cstdint>
#include <cstddef>

// LowRankRNN: h_{t+1} = h + coef*(-h + J@relu(h) + I_t),  J = G*W - B/N + M u v^T
//
// Persistent kernel, 64 blocks x 512 threads, J in registers. Sync protocol:
// sign-bit-encoded data IS the flag (x = relu(h) >= 0; x(t) stored with sign
// bit forced to phase enc(t)=(t>>1)&1; decode = clear sign bit; two buffers
// alternate by t&1 so stale data never satisfies a poll).
//
// R5 changes vs R4 (numerics bit-identical: same FMA order, same reduce):
//  1. Publish REPLICATION xR: after the allreduce every lane holds h[], so
//     lanes 0..R-1 store the same encoded 16B to R replica x-buffers (one
//     store instr). Block b polls replica b&(R-1): coherent readers per LLC
//     line drop 64 -> 64/R, removing hot-line slice serialization.
//     R chosen at launch from ws_size (8 if 128KB fits).
//  2. NO __syncthreads in the loop: the sign-phase protocol extends into LDS.
//     Each wave writes its ENCODED chunk to LDS immediately on global-poll
//     success; consumers batch-read all 8 chunks (one asm block: 8x
//     ds_read_b128 + single lgkmcnt(0), ~200cy/round) and re-read until all
//     32 dwords match the phase, then decode in-register. Removes the
//     slowest-of-8 barrier coupling.
//     WAR safety: a wave at step t+2 implies x(t+1) fully published, which
//     implies every wave of every block finished its step-t LDS reads (each
//     wave publishes only after its own reduce, i.e. after its LDS reads).
//     LDS init = sign-set (-0.0f) + one pre-loop barrier, so garbage cannot
//     fake-pass phase-0's sign-clear check; slots alternate phase thereafter.
//
// Overwrite safety (global buffers) unchanged: publishing x(t+2) requires
// having acquired all of x(t+1), which certifies all step-t reads are done.

constexpr int   NN   = 2048;
constexpr int   TT   = 8192;
constexpr float COEF = 0.001f;             // DT/TAU
constexpr float G_   = 2.0f;
constexpr float BOFF = 10.0f / 2048.0f;    // B/N
constexpr float M_   = 1.5f;

constexpr int NBLK = 64;
constexpr int TPB  = 512;   // 8 waves
constexpr int WPB  = TPB / 64;

typedef float f32x4 __attribute__((ext_vector_type(4)));
typedef int   i32x4 __attribute__((ext_vector_type(4)));

__device__ __forceinline__ i32x4 bc(const f32x4 x) { return __builtin_bit_cast(i32x4, x); }
__device__ __forceinline__ f32x4 fc(const i32x4 x) { return __builtin_bit_cast(f32x4, x); }

// Layout: xbuf[replica][phase][NN]. phase0 polled first at t=2 expecting
// sign-SET -> init clear (0.0f blocks). phase1 polled first at t=1 expecting
// sign-CLEAR -> init set (-1.0f blocks). phase = bit 11 of linear index.
__global__ void init_xbufs(float* xb, int total) {
  const int i = blockIdx.x * blockDim.x + threadIdx.x;
  if (i < total) xb[i] = ((i >> 11) & 1) ? -1.0f : 0.0f;
}

// One LLC-coherent 16B load + waitcnt inside one asm block (consumers are
// ordered by register dataflow; rule-#18 safe).
__device__ __forceinline__ f32x4 poll1(const float* p) {
  f32x4 c;
  asm volatile("global_load_dwordx4 %0, %1, off sc0 sc1\n\t"
               "s_waitcnt vmcnt(0)"
               : "=&v"(c) : "v"(p) : "memory");
  return c;
}

// write-through 16B publish store (visible at LLC; per-dword atomicity)
__device__ __forceinline__ void store_wt(float* p, f32x4 v) {
  asm volatile("global_store_dwordx4 %0, %1, off sc0 sc1"
               :: "v"(p), "v"(v) : "memory");
}

// LDS: batched read of all 8 chunks (pipelined, one waitcnt) and prompt write.
// addr = LDS byte offset (low 32 bits of a flat shared pointer).
__device__ __forceinline__ void lds_read8(unsigned addr, f32x4 x[8]) {
  asm volatile(
      "ds_read_b128 %0, %8 offset:0\n\t"
      "ds_read_b128 %1, %8 offset:1024\n\t"
      "ds_read_b128 %2, %8 offset:2048\n\t"
      "ds_read_b128 %3, %8 offset:3072\n\t"
      "ds_read_b128 %4, %8 offset:4096\n\t"
      "ds_read_b128 %5, %8 offset:5120\n\t"
      "ds_read_b128 %6, %8 offset:6144\n\t"
      "ds_read_b128 %7, %8 offset:7168\n\t"
      "s_waitcnt lgkmcnt(0)"
      : "=&v"(x[0]), "=&v"(x[1]), "=&v"(x[2]), "=&v"(x[3]),
        "=&v"(x[4]), "=&v"(x[5]), "=&v"(x[6]), "=&v"(x[7])
      : "v"(addr)
      : "memory");
}
__device__ __forceinline__ void lds_write16(unsigned addr, f32x4 v) {
  asm volatile("ds_write_b128 %0, %1" :: "v"(addr), "v"(v) : "memory");
}

// butterfly helpers — value-identical to p += __shfl_xor(p, m)
template <int CTRL>
__device__ __forceinline__ float xadd_dpp(float v) {
  const int t = __builtin_amdgcn_update_dpp(0, __builtin_bit_cast(int, v),
                                            CTRL, 0xF, 0xF, false);
  return v + __builtin_bit_cast(float, t);
}
template <int PAT>
__device__ __forceinline__ float xadd_swz(float v) {
  const int t = __builtin_amdgcn_ds_swizzle(__builtin_bit_cast(int, v), PAT);
  return v + __builtin_bit_cast(float, t);
}

__global__ __launch_bounds__(TPB, 1)
void rnn_persist(const float* __restrict__ I_t,
                 const float* __restrict__ h0,
                 const float* __restrict__ W,
                 const float* __restrict__ u,
                 const float* __restrict__ v,
                 float* __restrict__ out_h,   // d_out + TT, [TT][NN]
                 float* __restrict__ xbuf,    // R * 2 * NN floats
                 int R)                        // replica count, power of 2
{
  __shared__ f32x4 xs[2][NN / 4];             // 16 KB, phase-encoded x

  const int tid = threadIdx.x;
  const int l   = tid & 63;
  const int w   = tid >> 6;
  const int gw  = blockIdx.x * WPB + w;           // global wave 0..511
  const int rb  = gw * 4;                         // this wave's 4 rows
  const int cb  = l * 4;                          // column base per 256-chunk
  const int rrep = blockIdx.x & (R - 1);          // replica this block polls

  // ---- J rows rb..rb+3: J[j][k] <-> row rb+j, cols k*256 + 4l
  f32x4 J[4][8];
#pragma unroll
  for (int j = 0; j < 4; ++j) {
    const float mu = M_ * u[rb + j];
#pragma unroll
    for (int k = 0; k < 8; ++k) {
      const int c = k * 256 + cb;
      const f32x4 wv = *(const f32x4*)(W + (size_t)(rb + j) * NN + c);
      const f32x4 vv = *(const f32x4*)(v + c);
      J[j][k] = G_ * wv - BOFF + mu * vv;
    }
  }

  float h[4];
#pragma unroll
  for (int j = 0; j < 4; ++j) h[j] = h0[rb + j];

  const f32x4 zero4 = {0.f, 0.f, 0.f, 0.f};
  const unsigned xs_base = (unsigned)(size_t)(&xs[0][0]);  // LDS byte offset

  // LDS init: both phases sign-SET (-0.0f) so no poll can fake-pass before
  // the first genuine write. One barrier, then none for the rest of the run.
  {
    const f32x4 m0 = {-0.0f, -0.0f, -0.0f, -0.0f};
    xs[0][tid] = m0;
    xs[1][tid] = m0;
    __syncthreads();
  }

  // I_t pipeline: parity-selected regs, issued ~1 step ahead of use
  f32x4 iva = *(const f32x4*)(I_t + rb);              // row 0
  f32x4 ivb = *(const f32x4*)(I_t + (size_t)NN + rb); // row 1 (in flight)

  for (int t = 0; t < TT; ++t) {
    const f32x4 icur4 = (t & 1) ? ivb : iva;
    const int  bsel = t & 1;
    const bool enc  = ((t >> 1) & 1) != 0;      // phase of x(t)

    // ---- acquire this wave's chunk w of x(t) (ENCODED; no decode here)
    f32x4 cenc;
    if (t == 0) {
      const f32x4 hv = *(const f32x4*)(h0 + w * 256 + cb);
      i32x4 b = bc(__builtin_elementwise_max(hv, zero4));
      b &= 0x7fffffff;   // force sign clear (phase 0), incl. any -0.0
      cenc = fc(b);
    } else {
      const float* pb = xbuf + (size_t)rrep * (2 * NN) + bsel * NN + w * 256 + cb;
      unsigned spins = 0;
      if (enc) {
        for (;;) {  // fresh: all 4 words sign SET
          cenc = poll1(pb);
          const i32x4 b = bc(cenc);
          if (__all(((b.x & b.y) & (b.z & b.w)) < 0)) break;
          if (++spins > (1u << 22)) break;
        }
      } else {
        for (;;) {  // fresh: all 4 words sign CLEAR
          cenc = poll1(pb);
          const i32x4 b = bc(cenc);
          if (__all(((b.x | b.y) | (b.z | b.w)) >= 0)) break;
          if (++spins > (1u << 22)) break;
        }
      }
    }

    // publish chunk to LDS immediately (encoded) — other waves are waiting
    lds_write16(xs_base + bsel * 8192 + w * 1024 + l * 16, cenc);

    // I_t row t+2: full step of slack before its consumer
    if (t + 2 < TT) {
      const f32x4 nv = *(const f32x4*)(I_t + (size_t)(t + 2) * NN + rb);
      if (t & 1) ivb = nv; else iva = nv;
    }

    // ---- LDS batch-poll all 8 chunks of x(t) (incl. own; always valid)
    f32x4 xv[8];
    {
      const unsigned raddr = xs_base + bsel * 8192 + l * 16;
      unsigned spins = 0;
      for (;;) {
        lds_read8(raddr, xv);
        const i32x4 a0 = bc(xv[0]), a1 = bc(xv[1]), a2 = bc(xv[2]), a3 = bc(xv[3]);
        const i32x4 a4 = bc(xv[4]), a5 = bc(xv[5]), a6 = bc(xv[6]), a7 = bc(xv[7]);
        if (enc) {
          i32x4 s = (a0 & a1) & (a2 & a3); s &= (a4 & a5) & (a6 & a7);
          if (__all(((s.x & s.y) & (s.z & s.w)) < 0)) break;
        } else {
          i32x4 s = (a0 | a1) | (a2 | a3); s |= (a4 | a5) | (a6 | a7);
          if (__all(((s.x | s.y) | (s.z | s.w)) >= 0)) break;
        }
        if (++spins > (1u << 20)) break;
      }
    }

    // ---- decode + p = J @ x (same accumulation order as R4: k = 0..7)
    f32x4 p4[4] = {zero4, zero4, zero4, zero4};
#pragma unroll
    for (int k = 0; k < 8; ++k) {
      i32x4 b = bc(xv[k]); b &= 0x7fffffff;       // clear sign = decode
      const f32x4 xd = fc(b);
#pragma unroll
      for (int j = 0; j < 4; ++j)
        p4[j] = __builtin_elementwise_fma(J[j][k], xd, p4[j]);  // v_pk_fma_f32
    }
    float p[4];
#pragma unroll
    for (int j = 0; j < 4; ++j)
      p[j] = (p4[j].x + p4[j].y) + (p4[j].z + p4[j].w);

    // wave allreduce — same pairing order as p += __shfl_xor(p, m), m=32..1
#pragma unroll
    for (int j = 0; j < 4; ++j) {
      p[j] += __shfl_xor(p[j], 32, 64);     // xor32
      p[j] = xadd_swz<0x401F>(p[j]);        // xor16
      p[j] = xadd_dpp<0x128>(p[j]);         // xor8  (row_ror:8)
      p[j] = xadd_swz<0x101F>(p[j]);        // xor4
      p[j] = xadd_dpp<0x4E>(p[j]);          // xor2  (quad_perm [2,3,0,1])
      p[j] = xadd_dpp<0xB1>(p[j]);          // xor1  (quad_perm [1,0,3,2])
    }

    const float ic[4] = {icur4.x, icur4.y, icur4.z, icur4.w};
#pragma unroll
    for (int j = 0; j < 4; ++j)
      h[j] = fmaf(COEF, p[j] + ic[j] - h[j], h[j]);

    // ---- publish x(t+1) encoded to R replicas (lanes 0..R-1; all lanes
    // hold h[] after the allreduce). This IS the global barrier.
    if (t + 1 < TT) {
      const bool encN = (((t + 1) >> 1) & 1) != 0;
      i32x4 e;
      e.x = __builtin_bit_cast(int, fmaxf(h[0], 0.f));
      e.y = __builtin_bit_cast(int, fmaxf(h[1], 0.f));
      e.z = __builtin_bit_cast(int, fmaxf(h[2], 0.f));
      e.w = __builtin_bit_cast(int, fmaxf(h[3], 0.f));
      if (encN) e |= 0x80000000; else e &= 0x7fffffff;
      if (l < R)
        store_wt(xbuf + (size_t)l * (2 * NN) + ((t + 1) & 1) * NN + rb, fc(e));
    }
    // trace store (cached; off the critical path)
    if (l == 0) {
      f32x4 hv; hv.x = h[0]; hv.y = h[1]; hv.z = h[2]; hv.w = h[3];
      *(f32x4*)(out_h + (size_t)t * NN + rb) = hv;
    }
  }
}

__global__ __launch_bounds__(256)
void readout(const float* __restrict__ h_all,
             const float* __restrict__ ro_w,
             const float* __restrict__ ro_b,
             float* __restrict__ y)
{
  __shared__ float red[4];
  const int t   = blockIdx.x;
  const int tid = threadIdx.x;
  const float* h = h_all + (size_t)t * NN;
  const int base = tid * 8;

  const float4 a0 = *(const float4*)(h + base);
  const float4 a1 = *(const float4*)(h + base + 4);
  const float4 w0 = *(const float4*)(ro_w + base);
  const float4 w1 = *(const float4*)(ro_w + base + 4);

  float s = a0.x * w0.x + a0.y * w0.y + a0.z * w0.z + a0.w * w0.w
          + a1.x * w1.x + a1.y * w1.y + a1.z * w1.z + a1.w * w1.w;
#pragma unroll
  for (int m = 32; m >= 1; m >>= 1) s += __shfl_xor(s, m, 64);

  if ((tid & 63) == 0) red[tid >> 6] = s;
  __syncthreads();
  if (tid == 0) y[t] = red[0] + red[1] + red[2] + red[3] + ro_b[0];
}

extern "C" void kernel_launch(void* const* d_in, const int* in_sizes, int n_in,
                              void* d_out, int out_size, void* d_ws, size_t ws_size,
                              hipStream_t stream)
{
  const float* I_t  = (const float*)d_in[0];
  const float* h0   = (const float*)d_in[1];
  const float* W    = (const float*)d_in[2];
  const float* u    = (const float*)d_in[3];
  const float* v    = (const float*)d_in[4];
  const float* ro_w = (const float*)d_in[5];
  const float* ro_b = (const float*)d_in[6];

  float* y    = (float*)d_out;             // [TT]
  float* outh = (float*)d_out + TT;        // [TT][NN]

  float* xbuf = (float*)d_ws;

  // replica count: as many as the workspace holds (power of 2, max 8)
  int R = 1;
  if      (ws_size >= (size_t)8 * 2 * NN * 4) R = 8;
  else if (ws_size >= (size_t)4 * 2 * NN * 4) R = 4;
  else if (ws_size >= (size_t)2 * 2 * NN * 4) R = 2;

  const int total = R * 2 * NN;
  init_xbufs<<<(total + TPB - 1) / TPB, TPB, 0, stream>>>(xbuf, total);
  rnn_persist<<<NBLK, TPB, 0, stream>>>(I_t, h0, W, u, v, outh, xbuf, R);
  readout<<<TT, 256, 0, stream>>>(outh, ro_w, ro_b, y);
}